// Round 3
// baseline (2435.291 us; speedup 1.0000x reference)
//
#include <hip/hip_runtime.h>
#include <math.h>

// Problem constants
#define NB   64            // batch
#define TT   2048          // time steps
#define BT   (NB*TT)       // 131072 rows
#define DIN  4
#define H0   64
#define DD   128
#define HD   256

// LIF chunking: 8 chunks of 256 steps, 64-step warmup (0.5^64 decay -> exact in fp32)
#define CHUNK 256
#define NCHUNK 8
#define WARM 64

__device__ __forceinline__ float gelu_exact(float x) {
    return 0.5f * x * (1.0f + erff(x * 0.7071067811865476f));
}

// ---------------- Projector stage 1: G = gelu(hist @ pw1 + pb1)  [BT,64] ----
__global__ void proj1_kernel(const float* __restrict__ hist, const float* __restrict__ pw1,
                             const float* __restrict__ pb1, float* __restrict__ G) {
    int tid = blockIdx.x * 256 + threadIdx.x;     // BT*64 threads
    int r = tid >> 6, j = tid & 63;
    const float* h = hist + (size_t)r * DIN;
    float acc = pb1[j];
    acc += h[0] * pw1[0*64 + j];
    acc += h[1] * pw1[1*64 + j];
    acc += h[2] * pw1[2*64 + j];
    acc += h[3] * pw1[3*64 + j];
    G[tid] = gelu_exact(acc);
}

// ---------------- Projector stage 2: X = G @ pw2 + pb2  [BT,128] ------------
// W (32KB) resident in LDS staged once; G rows via wave-uniform s_load_dwordx4
// (scalar pipe) -> inner loop LDS issues are w-reads only.
__global__ void __launch_bounds__(512) proj2_kernel(const float* __restrict__ G,
        const float* __restrict__ pw2, const float* __restrict__ pb2,
        float* __restrict__ X) {
    __shared__ float Wc[64*128];     // 32KB
    int wave = threadIdx.x >> 6, lane = threadIdx.x & 63;
    for (int i = threadIdx.x; i < 64*128/4; i += 512)
        ((float4*)Wc)[i] = ((const float4*)pw2)[i];
    __syncthreads();
    float2 bv = ((const float2*)pb2)[lane];
    for (int tile = blockIdx.x * 8 + wave; tile < BT/8; tile += 4096) {
        int rb = __builtin_amdgcn_readfirstlane(tile) * 8;
        const float* __restrict__ x0 = G + (size_t)rb * 64;
        float2 acc[8];
        #pragma unroll
        for (int r = 0; r < 8; ++r) acc[r] = make_float2(0.f, 0.f);
        #pragma unroll 2
        for (int k4 = 0; k4 < 16; ++k4) {
            float4 xr[8];
            #pragma unroll
            for (int r = 0; r < 8; ++r)
                xr[r] = *(const float4*)(x0 + r*64 + k4*4);   // s_load_dwordx4
            #pragma unroll
            for (int kk = 0; kk < 4; ++kk) {
                float2 w = ((const float2*)(Wc + (k4*4 + kk)*128))[lane];
                #pragma unroll
                for (int r = 0; r < 8; ++r) {
                    float xv = ((const float*)&xr[r])[kk];    // SGPR operand
                    acc[r].x += xv * w.x;
                    acc[r].y += xv * w.y;
                }
            }
        }
        #pragma unroll
        for (int r = 0; r < 8; ++r) {
            float2 o; o.x = acc[r].x + bv.x; o.y = acc[r].y + bv.y;
            ((float2*)(X + (size_t)(rb + r) * 128))[lane] = o;
        }
    }
}

// ---------------- fc1 + LayerNorm: Hout = LN(X @ W1 + b1)  [BT,256] ---------
// W in 64KB K-halves; x rows via s_load_dwordx4 (scalar pipe). Inner loop LDS
// = 4 ds_read_b128 per 128 v_fmac -> FMA-bound.
__global__ void __launch_bounds__(512) fc1_kernel(const float* __restrict__ Xin,
        const float* __restrict__ W, const float* __restrict__ bias,
        const float* __restrict__ gamma, const float* __restrict__ beta,
        float* __restrict__ Hout) {
    __shared__ float Wc[64*256];     // 64KB: K-half (64 x 256)
    int wave = threadIdx.x >> 6, lane = threadIdx.x & 63;
    float4 bv  = ((const float4*)bias)[lane];
    float4 gv  = ((const float4*)gamma)[lane];
    float4 btv = ((const float4*)beta)[lane];
    for (int tile = blockIdx.x * 8 + wave; tile < BT/8; tile += 4096) {
        int rb = __builtin_amdgcn_readfirstlane(tile) * 8;
        const float* __restrict__ x0 = Xin + (size_t)rb * 128;
        float4 acc[8];
        #pragma unroll
        for (int r = 0; r < 8; ++r) acc[r] = make_float4(0.f,0.f,0.f,0.f);
        for (int h = 0; h < 2; ++h) {
            __syncthreads();   // previous use of Wc complete (all waves same trip)
            const float4* Wh = (const float4*)(W + h*64*256);
            for (int i = threadIdx.x; i < 64*256/4; i += 512)
                ((float4*)Wc)[i] = Wh[i];
            __syncthreads();
            const float* __restrict__ xh = x0 + h*64;
            #pragma unroll 2
            for (int k4 = 0; k4 < 16; ++k4) {
                float4 xr[8];
                #pragma unroll
                for (int r = 0; r < 8; ++r)
                    xr[r] = *(const float4*)(xh + r*128 + k4*4);   // s_load_dwordx4
                #pragma unroll
                for (int kk = 0; kk < 4; ++kk) {
                    float4 w = ((const float4*)(Wc + (k4*4 + kk)*256))[lane];
                    #pragma unroll
                    for (int r = 0; r < 8; ++r) {
                        float xv = ((const float*)&xr[r])[kk];     // SGPR operand
                        acc[r].x += xv * w.x; acc[r].y += xv * w.y;
                        acc[r].z += xv * w.z; acc[r].w += xv * w.w;
                    }
                }
            }
        }
        #pragma unroll
        for (int r = 0; r < 8; ++r) {
            float4 a = acc[r];
            a.x += bv.x; a.y += bv.y; a.z += bv.z; a.w += bv.w;
            float s = a.x + a.y + a.z + a.w;
            #pragma unroll
            for (int m = 1; m < 64; m <<= 1) s += __shfl_xor(s, m, 64);
            float mean = s * (1.0f/256.0f);
            float dx = a.x - mean, dy = a.y - mean, dz = a.z - mean, dw = a.w - mean;
            float q2 = dx*dx + dy*dy + dz*dz + dw*dw;
            #pragma unroll
            for (int m = 1; m < 64; m <<= 1) q2 += __shfl_xor(q2, m, 64);
            float inv = 1.0f / sqrtf(q2 * (1.0f/256.0f) + 1e-5f);
            float4 o;
            o.x = dx*inv*gv.x + btv.x; o.y = dy*inv*gv.y + btv.y;
            o.z = dz*inv*gv.z + btv.z; o.w = dw*inv*gv.w + btv.w;
            ((float4*)(Hout + (size_t)(rb + r) * 256))[lane] = o;
        }
    }
}

// ---------------- LIF1 pass A: membrane state at chunk starts ---------------
// Chunk c's warmup window [c*256-64, c*256) is owned (and later overwritten)
// by chunk c-1 in the in-place pass, so pre-compute warmup v here while H is
// still pristine fc1 output.
__global__ void lif1a_kernel(const float* __restrict__ H, float* __restrict__ V0) {
    int tid = blockIdx.x * 256 + threadIdx.x;     // 7*64*256 threads
    int d = tid & 255;
    int rest = tid >> 8;
    int b = rest & 63;
    int c = (rest >> 6) + 1;                       // chunk 1..7
    int t0 = c * CHUNK;
    const float* __restrict__ hp = H + ((size_t)b * TT + (t0 - WARM)) * 256 + d;
    float v = 0.f;
    #pragma unroll 8
    for (int t = 0; t < WARM; ++t) {
        float x = *hp; hp += 256;
        v += (x - v) * 0.5f;
        v = (v >= 1.0f) ? 0.f : v;
    }
    V0[tid] = v;
}

// ---------------- LIF1 pass B: in-place H -> spike floats (0.0/1.0) ---------
__global__ void lif1b_kernel(float* __restrict__ H, const float* __restrict__ V0) {
    int tid = blockIdx.x * 256 + threadIdx.x;     // 8*64*256 threads
    int d = tid & 255;
    int rest = tid >> 8;
    int b = rest & 63;
    int c = rest >> 6;                             // chunk 0..7
    int t0 = c * CHUNK;
    float v = (c == 0) ? 0.f : V0[((c-1)*64 + b)*256 + d];
    float* __restrict__ hp = H + ((size_t)b * TT + t0) * 256 + d;
    #pragma unroll 8
    for (int t = 0; t < CHUNK; ++t) {
        float x = *hp;
        v += (x - v) * 0.5f;
        bool s = (v >= 1.0f);
        *hp = s ? 1.0f : 0.0f;
        hp += 256;
        v = s ? 0.f : v;
    }
}

// ---------------- fc2 + LayerNorm: Y = LN(SF @ W2 + b2)  [half-batch,128] ---
// Identical structure to fc1 (spikes are f32 in SF): W2 in 64KB K-halves,
// rows via s_load_dwordx4. Runs per half-batch so Y fits 32MB.
__global__ void __launch_bounds__(512) fc2_kernel(const float* __restrict__ SF,
        const float* __restrict__ W, const float* __restrict__ bias,
        const float* __restrict__ gamma, const float* __restrict__ beta,
        float* __restrict__ Y) {
    __shared__ float Wc[128*128];    // 64KB: K-half (128 x 128)
    int wave = threadIdx.x >> 6, lane = threadIdx.x & 63;
    float2 bv  = ((const float2*)bias)[lane];
    float2 gv  = ((const float2*)gamma)[lane];
    float2 btv = ((const float2*)beta)[lane];
    for (int tile = blockIdx.x * 8 + wave; tile < (BT/2)/8; tile += 4096) {
        int rb = __builtin_amdgcn_readfirstlane(tile) * 8;
        const float* __restrict__ x0 = SF + (size_t)rb * 256;
        float2 acc[8];
        #pragma unroll
        for (int r = 0; r < 8; ++r) acc[r] = make_float2(0.f, 0.f);
        for (int h = 0; h < 2; ++h) {
            __syncthreads();
            const float4* Wh = (const float4*)(W + h*128*128);
            for (int i = threadIdx.x; i < 128*128/4; i += 512)
                ((float4*)Wc)[i] = Wh[i];
            __syncthreads();
            const float* __restrict__ xh = x0 + h*128;
            #pragma unroll 2
            for (int k4 = 0; k4 < 32; ++k4) {
                float4 xr[8];
                #pragma unroll
                for (int r = 0; r < 8; ++r)
                    xr[r] = *(const float4*)(xh + r*256 + k4*4);   // s_load_dwordx4
                #pragma unroll
                for (int kk = 0; kk < 4; ++kk) {
                    float2 w = ((const float2*)(Wc + (k4*4 + kk)*128))[lane];
                    #pragma unroll
                    for (int r = 0; r < 8; ++r) {
                        float xv = ((const float*)&xr[r])[kk];
                        acc[r].x += xv * w.x;
                        acc[r].y += xv * w.y;
                    }
                }
            }
        }
        #pragma unroll
        for (int r = 0; r < 8; ++r) {
            float2 a = acc[r];
            a.x += bv.x; a.y += bv.y;
            float s = a.x + a.y;
            #pragma unroll
            for (int m = 1; m < 64; m <<= 1) s += __shfl_xor(s, m, 64);
            float mean = s * (1.0f/128.0f);
            float dx = a.x - mean, dy = a.y - mean;
            float q = dx*dx + dy*dy;
            #pragma unroll
            for (int m = 1; m < 64; m <<= 1) q += __shfl_xor(q, m, 64);
            float inv = 1.0f / sqrtf(q * (1.0f/128.0f) + 1e-5f);
            float2 o;
            o.x = dx*inv*gv.x + btv.x;
            o.y = dy*inv*gv.y + btv.y;
            ((float2*)(Y + (size_t)(rb + r) * 128))[lane] = o;
        }
    }
}

// ---------------- LIF2 + residual add into X; optional final output --------
// Y is half-batch local [32*TT,128]; X/out indexed with global b = b0 + bl.
__global__ void lif2_kernel(const float* __restrict__ Y, float* __restrict__ X,
                            float* __restrict__ out, int b0, int writeOut) {
    int tid = blockIdx.x * 256 + threadIdx.x;     // 32*8*128 = 32768 threads
    int n = tid & 127;
    int rest = tid >> 7;
    int bl = rest & 31;
    int c = rest >> 5;                             // chunk 0..7
    int b = b0 + bl;
    int t0 = c * CHUNK;
    int tw = (c == 0) ? 0 : (t0 - WARM);
    const float* __restrict__ yp = Y + ((size_t)bl * TT + tw) * 128 + n;
    float v = 0.f;
    #pragma unroll 8
    for (int t = tw; t < t0; ++t) {
        float x = *yp; yp += 128;
        v += (x - v) * 0.5f;
        v = (v >= 1.0f) ? 0.f : v;
    }
    float* __restrict__ xp = X + ((size_t)b * TT + t0) * 128 + n;
    #pragma unroll 4
    for (int t = 0; t < CHUNK; ++t) {
        float x = *yp; yp += 128;
        v += (x - v) * 0.5f;
        bool s = (v >= 1.0f);
        bool last = (writeOut != 0) && ((t0 + t) == (TT - 1));
        if (s) {
            float xv = xp[(size_t)t * 128] + 1.0f;
            xp[(size_t)t * 128] = xv;
            if (last) out[b * 128 + n] = xv;
        } else if (last) {
            out[b * 128 + n] = xp[(size_t)t * 128];
        }
        v = s ? 0.f : v;
    }
}

extern "C" void kernel_launch(void* const* d_in, const int* in_sizes, int n_in,
                              void* d_out, int out_size, void* d_ws, size_t ws_size,
                              hipStream_t stream) {
    const float* hist = (const float*)d_in[0];
    const float* pw1  = (const float*)d_in[1];
    const float* pb1  = (const float*)d_in[2];
    const float* pw2  = (const float*)d_in[3];
    const float* pb2  = (const float*)d_in[4];
    const float* fc1w = (const float*)d_in[5];
    const float* fc1b = (const float*)d_in[6];
    const float* n1g  = (const float*)d_in[7];
    const float* n1b  = (const float*)d_in[8];
    const float* fc2w = (const float*)d_in[9];
    const float* fc2b = (const float*)d_in[10];
    const float* n2g  = (const float*)d_in[11];
    const float* n2b  = (const float*)d_in[12];
    float* out = (float*)d_out;

    char* ws = (char*)d_ws;
    float* X  = (float*)ws;                                    // [BT,128] f32: 64 MiB
    float* H  = (float*)(ws + (size_t)67108864);               // [BT,256] f32: 128 MiB (G / fc1-out / spike-f32)
    float* YR = (float*)(ws + (size_t)67108864 + 134217728);   // 32 MiB region @192MiB
    float* V0 = YR;        // lif1 warmup states (448KB), dead before Y written
    float* Y  = YR;        // fc2 half-batch output [32*TT,128] = 32 MiB
    float* G  = H;         // projector hidden reuses H region

    proj1_kernel<<<BT*64/256, 256, 0, stream>>>(hist, pw1, pb1, G);
    proj2_kernel<<<512, 512, 0, stream>>>(G, pw2, pb2, X);
    for (int i = 0; i < 4; ++i) {
        fc1_kernel<<<512, 512, 0, stream>>>(X, fc1w + (size_t)i*128*256,
                                            fc1b + i*256, n1g + i*256, n1b + i*256, H);
        lif1a_kernel<<<7*64*256/256, 256, 0, stream>>>(H, V0);
        lif1b_kernel<<<BT/256 , 256, 0, stream>>>(H, V0);
        int wo = (i == 3) ? 1 : 0;
        for (int half = 0; half < 2; ++half) {
            const float* SF = H + (size_t)half * 32 * TT * 256;
            fc2_kernel<<<512, 512, 0, stream>>>(SF, fc2w + (size_t)i*256*128,
                                                fc2b + i*128, n2g + i*128, n2b + i*128, Y);
            lif2_kernel<<<128, 256, 0, stream>>>(Y, X, out, half*32, wo);
        }
    }
}

// Round 4
// 1451.646 us; speedup vs baseline: 1.6776x; 1.6776x over previous
//
#include <hip/hip_runtime.h>
#include <math.h>

// Problem constants
#define NB   64            // batch
#define TT   2048          // time steps
#define BT   (NB*TT)       // 131072 rows
#define DIN  4
#define H0   64
#define DD   128
#define HD   256

// LIF1 chunking: 8 chunks of 256 steps, 64-step warmup (0.5^64 decay -> exact in fp32)
#define CHUNK 256
#define NCHUNK 8
#define WARM 64
// LIF2 chunking: 16 chunks of 128 (more parallelism; X update is unconditional)
#define CHUNK2 128
#define NCHUNK2 16

__device__ __forceinline__ float gelu_exact(float x) {
    return 0.5f * x * (1.0f + erff(x * 0.7071067811865476f));
}

// ---------------- Projector stage 1: G = gelu(hist @ pw1 + pb1)  [BT,64] ----
__global__ void proj1_kernel(const float* __restrict__ hist, const float* __restrict__ pw1,
                             const float* __restrict__ pb1, float* __restrict__ G) {
    int tid = blockIdx.x * 256 + threadIdx.x;     // BT*64 threads
    int r = tid >> 6, j = tid & 63;
    const float* h = hist + (size_t)r * DIN;
    float acc = pb1[j];
    acc += h[0] * pw1[0*64 + j];
    acc += h[1] * pw1[1*64 + j];
    acc += h[2] * pw1[2*64 + j];
    acc += h[3] * pw1[3*64 + j];
    G[tid] = gelu_exact(acc);
}

// ---------------- Projector stage 2: X = G @ pw2 + pb2  [BT,128] ------------
__global__ void __launch_bounds__(512) proj2_kernel(const float* __restrict__ G,
        const float* __restrict__ pw2, const float* __restrict__ pb2,
        float* __restrict__ X) {
    __shared__ float Wc[64*128];     // 32KB
    int wave = threadIdx.x >> 6, lane = threadIdx.x & 63;
    for (int i = threadIdx.x; i < 64*128/4; i += 512)
        ((float4*)Wc)[i] = ((const float4*)pw2)[i];
    __syncthreads();
    float2 bv = ((const float2*)pb2)[lane];
    for (int tile = blockIdx.x * 8 + wave; tile < BT/8; tile += 4096) {
        int rb = __builtin_amdgcn_readfirstlane(tile) * 8;
        const float* __restrict__ x0 = G + (size_t)rb * 64;
        float2 acc[8];
        #pragma unroll
        for (int r = 0; r < 8; ++r) acc[r] = make_float2(0.f, 0.f);
        #pragma unroll 2
        for (int k4 = 0; k4 < 16; ++k4) {
            float4 xr[8];
            #pragma unroll
            for (int r = 0; r < 8; ++r)
                xr[r] = *(const float4*)(x0 + r*64 + k4*4);   // s_load_dwordx4
            #pragma unroll
            for (int kk = 0; kk < 4; ++kk) {
                float2 w = ((const float2*)(Wc + (k4*4 + kk)*128))[lane];
                #pragma unroll
                for (int r = 0; r < 8; ++r) {
                    float xv = ((const float*)&xr[r])[kk];    // SGPR operand
                    acc[r].x += xv * w.x;
                    acc[r].y += xv * w.y;
                }
            }
        }
        #pragma unroll
        for (int r = 0; r < 8; ++r) {
            float2 o; o.x = acc[r].x + bv.x; o.y = acc[r].y + bv.y;
            ((float2*)(X + (size_t)(rb + r) * 128))[lane] = o;
        }
    }
}

// ---------------- fc1 + LayerNorm: Hout = LN(X @ W1 + b1)  [BT,256] ---------
__global__ void __launch_bounds__(512) fc1_kernel(const float* __restrict__ Xin,
        const float* __restrict__ W, const float* __restrict__ bias,
        const float* __restrict__ gamma, const float* __restrict__ beta,
        float* __restrict__ Hout) {
    __shared__ float Wc[64*256];     // 64KB: K-half (64 x 256)
    int wave = threadIdx.x >> 6, lane = threadIdx.x & 63;
    float4 bv  = ((const float4*)bias)[lane];
    float4 gv  = ((const float4*)gamma)[lane];
    float4 btv = ((const float4*)beta)[lane];
    for (int tile = blockIdx.x * 8 + wave; tile < BT/8; tile += 4096) {
        int rb = __builtin_amdgcn_readfirstlane(tile) * 8;
        const float* __restrict__ x0 = Xin + (size_t)rb * 128;
        float4 acc[8];
        #pragma unroll
        for (int r = 0; r < 8; ++r) acc[r] = make_float4(0.f,0.f,0.f,0.f);
        for (int h = 0; h < 2; ++h) {
            __syncthreads();
            const float4* Wh = (const float4*)(W + h*64*256);
            for (int i = threadIdx.x; i < 64*256/4; i += 512)
                ((float4*)Wc)[i] = Wh[i];
            __syncthreads();
            const float* __restrict__ xh = x0 + h*64;
            #pragma unroll 2
            for (int k4 = 0; k4 < 16; ++k4) {
                float4 xr[8];
                #pragma unroll
                for (int r = 0; r < 8; ++r)
                    xr[r] = *(const float4*)(xh + r*128 + k4*4);   // s_load_dwordx4
                #pragma unroll
                for (int kk = 0; kk < 4; ++kk) {
                    float4 w = ((const float4*)(Wc + (k4*4 + kk)*256))[lane];
                    #pragma unroll
                    for (int r = 0; r < 8; ++r) {
                        float xv = ((const float*)&xr[r])[kk];     // SGPR operand
                        acc[r].x += xv * w.x; acc[r].y += xv * w.y;
                        acc[r].z += xv * w.z; acc[r].w += xv * w.w;
                    }
                }
            }
        }
        #pragma unroll
        for (int r = 0; r < 8; ++r) {
            float4 a = acc[r];
            a.x += bv.x; a.y += bv.y; a.z += bv.z; a.w += bv.w;
            float s = a.x + a.y + a.z + a.w;
            #pragma unroll
            for (int m = 1; m < 64; m <<= 1) s += __shfl_xor(s, m, 64);
            float mean = s * (1.0f/256.0f);
            float dx = a.x - mean, dy = a.y - mean, dz = a.z - mean, dw = a.w - mean;
            float q2 = dx*dx + dy*dy + dz*dz + dw*dw;
            #pragma unroll
            for (int m = 1; m < 64; m <<= 1) q2 += __shfl_xor(q2, m, 64);
            float inv = 1.0f / sqrtf(q2 * (1.0f/256.0f) + 1e-5f);
            float4 o;
            o.x = dx*inv*gv.x + btv.x; o.y = dy*inv*gv.y + btv.y;
            o.z = dz*inv*gv.z + btv.z; o.w = dw*inv*gv.w + btv.w;
            ((float4*)(Hout + (size_t)(rb + r) * 256))[lane] = o;
        }
    }
}

// ---------------- LIF1 pass A: membrane state at chunk starts ---------------
__global__ void lif1a_kernel(const float* __restrict__ H, float* __restrict__ V0) {
    int tid = blockIdx.x * 256 + threadIdx.x;     // 7*64*256 threads
    int d = tid & 255;
    int rest = tid >> 8;
    int b = rest & 63;
    int c = (rest >> 6) + 1;                       // chunk 1..7
    int t0 = c * CHUNK;
    const float* __restrict__ hp = H + ((size_t)b * TT + (t0 - WARM)) * 256 + d;
    float v = 0.f;
    #pragma unroll 8
    for (int t = 0; t < WARM; ++t) {
        float x = *hp; hp += 256;
        v += (x - v) * 0.5f;
        v = (v >= 1.0f) ? 0.f : v;
    }
    V0[tid] = v;
}

// ---------------- LIF1 pass B: in-place H -> spike floats (0.0/1.0) ---------
__global__ void lif1b_kernel(float* __restrict__ H, const float* __restrict__ V0) {
    int tid = blockIdx.x * 256 + threadIdx.x;     // 8*64*256 threads
    int d = tid & 255;
    int rest = tid >> 8;
    int b = rest & 63;
    int c = rest >> 6;                             // chunk 0..7
    int t0 = c * CHUNK;
    float v = (c == 0) ? 0.f : V0[((c-1)*64 + b)*256 + d];
    float* __restrict__ hp = H + ((size_t)b * TT + t0) * 256 + d;
    #pragma unroll 8
    for (int t = 0; t < CHUNK; ++t) {
        float x = *hp;
        v += (x - v) * 0.5f;
        bool s = (v >= 1.0f);
        *hp = s ? 1.0f : 0.0f;
        hp += 256;
        v = s ? 0.f : v;
    }
}

// ---------------- fc2 + LayerNorm: Y = LN(SF @ W2 + b2)  [half-batch,128] ---
__global__ void __launch_bounds__(512) fc2_kernel(const float* __restrict__ SF,
        const float* __restrict__ W, const float* __restrict__ bias,
        const float* __restrict__ gamma, const float* __restrict__ beta,
        float* __restrict__ Y) {
    __shared__ float Wc[128*128];    // 64KB: K-half (128 x 128)
    int wave = threadIdx.x >> 6, lane = threadIdx.x & 63;
    float2 bv  = ((const float2*)bias)[lane];
    float2 gv  = ((const float2*)gamma)[lane];
    float2 btv = ((const float2*)beta)[lane];
    for (int tile = blockIdx.x * 8 + wave; tile < (BT/2)/8; tile += 4096) {
        int rb = __builtin_amdgcn_readfirstlane(tile) * 8;
        const float* __restrict__ x0 = SF + (size_t)rb * 256;
        float2 acc[8];
        #pragma unroll
        for (int r = 0; r < 8; ++r) acc[r] = make_float2(0.f, 0.f);
        for (int h = 0; h < 2; ++h) {
            __syncthreads();
            const float4* Wh = (const float4*)(W + h*128*128);
            for (int i = threadIdx.x; i < 128*128/4; i += 512)
                ((float4*)Wc)[i] = Wh[i];
            __syncthreads();
            const float* __restrict__ xh = x0 + h*128;
            #pragma unroll 2
            for (int k4 = 0; k4 < 32; ++k4) {
                float4 xr[8];
                #pragma unroll
                for (int r = 0; r < 8; ++r)
                    xr[r] = *(const float4*)(xh + r*256 + k4*4);   // s_load_dwordx4
                #pragma unroll
                for (int kk = 0; kk < 4; ++kk) {
                    float2 w = ((const float2*)(Wc + (k4*4 + kk)*128))[lane];
                    #pragma unroll
                    for (int r = 0; r < 8; ++r) {
                        float xv = ((const float*)&xr[r])[kk];
                        acc[r].x += xv * w.x;
                        acc[r].y += xv * w.y;
                    }
                }
            }
        }
        #pragma unroll
        for (int r = 0; r < 8; ++r) {
            float2 a = acc[r];
            a.x += bv.x; a.y += bv.y;
            float s = a.x + a.y;
            #pragma unroll
            for (int m = 1; m < 64; m <<= 1) s += __shfl_xor(s, m, 64);
            float mean = s * (1.0f/128.0f);
            float dx = a.x - mean, dy = a.y - mean;
            float q = dx*dx + dy*dy;
            #pragma unroll
            for (int m = 1; m < 64; m <<= 1) q += __shfl_xor(q, m, 64);
            float inv = 1.0f / sqrtf(q * (1.0f/128.0f) + 1e-5f);
            float2 o;
            o.x = dx*inv*gv.x + btv.x;
            o.y = dy*inv*gv.y + btv.y;
            ((float2*)(Y + (size_t)(rb + r) * 128))[lane] = o;
        }
    }
}

// ---------------- LIF2 + residual add into X; optional final output --------
// Unconditional X load/add/store: X traffic is off the membrane dependency
// chain -> prefetchable. 16 chunks of 128 steps for occupancy.
__global__ void lif2_kernel(const float* __restrict__ Y, float* __restrict__ X,
                            float* __restrict__ out, int b0, int writeOut) {
    int tid = blockIdx.x * 256 + threadIdx.x;     // 32*16*128 = 65536 threads
    int n = tid & 127;
    int rest = tid >> 7;
    int bl = rest & 31;
    int c = rest >> 5;                             // chunk 0..15
    int b = b0 + bl;
    int t0 = c * CHUNK2;
    int tw = (c == 0) ? 0 : (t0 - WARM);
    const float* __restrict__ yp = Y + ((size_t)bl * TT + tw) * 128 + n;
    float v = 0.f;
    #pragma unroll 8
    for (int t = tw; t < t0; ++t) {
        float x = *yp; yp += 128;
        v += (x - v) * 0.5f;
        v = (v >= 1.0f) ? 0.f : v;
    }
    float* __restrict__ xp = X + ((size_t)b * TT + t0) * 128 + n;
    float xlast = 0.f;
    #pragma unroll 8
    for (int t = 0; t < CHUNK2; ++t) {
        float y = *yp; yp += 128;
        v += (y - v) * 0.5f;
        bool s = (v >= 1.0f);
        float x = xp[(size_t)t * 128];             // unconditional, prefetchable
        x += s ? 1.0f : 0.0f;
        xp[(size_t)t * 128] = x;                   // unconditional store
        xlast = x;
        v = s ? 0.f : v;
    }
    if (writeOut && c == NCHUNK2 - 1)
        out[b * 128 + n] = xlast;
}

extern "C" void kernel_launch(void* const* d_in, const int* in_sizes, int n_in,
                              void* d_out, int out_size, void* d_ws, size_t ws_size,
                              hipStream_t stream) {
    const float* hist = (const float*)d_in[0];
    const float* pw1  = (const float*)d_in[1];
    const float* pb1  = (const float*)d_in[2];
    const float* pw2  = (const float*)d_in[3];
    const float* pb2  = (const float*)d_in[4];
    const float* fc1w = (const float*)d_in[5];
    const float* fc1b = (const float*)d_in[6];
    const float* n1g  = (const float*)d_in[7];
    const float* n1b  = (const float*)d_in[8];
    const float* fc2w = (const float*)d_in[9];
    const float* fc2b = (const float*)d_in[10];
    const float* n2g  = (const float*)d_in[11];
    const float* n2b  = (const float*)d_in[12];
    float* out = (float*)d_out;

    char* ws = (char*)d_ws;
    float* X  = (float*)ws;                                    // [BT,128] f32: 64 MiB
    float* H  = (float*)(ws + (size_t)67108864);               // [BT,256] f32: 128 MiB (G / fc1-out / spike-f32)
    float* YR = (float*)(ws + (size_t)67108864 + 134217728);   // 32 MiB region @192MiB
    float* V0 = YR;        // lif1 warmup states (448KB), dead before Y written
    float* Y  = YR;        // fc2 half-batch output [32*TT,128] = 32 MiB
    float* G  = H;         // projector hidden reuses H region

    proj1_kernel<<<BT*64/256, 256, 0, stream>>>(hist, pw1, pb1, G);
    proj2_kernel<<<512, 512, 0, stream>>>(G, pw2, pb2, X);
    for (int i = 0; i < 4; ++i) {
        fc1_kernel<<<512, 512, 0, stream>>>(X, fc1w + (size_t)i*128*256,
                                            fc1b + i*256, n1g + i*256, n1b + i*256, H);
        lif1a_kernel<<<7*64*256/256, 256, 0, stream>>>(H, V0);
        lif1b_kernel<<<BT/256 , 256, 0, stream>>>(H, V0);
        int wo = (i == 3) ? 1 : 0;
        for (int half = 0; half < 2; ++half) {
            const float* SF = H + (size_t)half * 32 * TT * 256;
            fc2_kernel<<<512, 512, 0, stream>>>(SF, fc2w + (size_t)i*256*128,
                                                fc2b + i*128, n2g + i*128, n2b + i*128, Y);
            lif2_kernel<<<256, 256, 0, stream>>>(Y, X, out, half*32, wo);
        }
    }
}

// Round 6
// 397.033 us; speedup vs baseline: 6.1337x; 3.6562x over previous
//
#include <hip/hip_runtime.h>
#include <math.h>

// Problem constants
#define NB   64
#define TT   2048
// Tail-window truncation: output = x[:, 2047]; the only temporal coupling is
// the LIF membrane (decay 0.5/step + hard reset). Computing t in [T0, 2048)
// with v(T0)=0 perturbs output-relevant spike decisions by <= 2*0.5^120 —
// strictly safer than the validated 64-step warmup of R4. 94% of work is dead.
#define TW   192
#define T0   (TT - TW)     // 1856
#define NR   (NB * TW)     // 12288 active rows

__device__ __forceinline__ float gelu_exact(float x) {
    return 0.5f * x * (1.0f + erff(x * 0.7071067811865476f));
}

// ---------------- Projector stage 1: G = gelu(hist @ pw1 + pb1)  [NR,64] ----
__global__ void proj1_kernel(const float* __restrict__ hist, const float* __restrict__ pw1,
                             const float* __restrict__ pb1, float* __restrict__ G) {
    int tid = blockIdx.x * 256 + threadIdx.x;     // NR*64 threads
    int r = tid >> 6, j = tid & 63;
    int b = r / TW, t = r - b * TW;                // window-local row -> (b, T0+t)
    const float* h = hist + ((size_t)b * TT + (T0 + t)) * 4;
    float acc = pb1[j];
    acc += h[0] * pw1[0*64 + j];
    acc += h[1] * pw1[1*64 + j];
    acc += h[2] * pw1[2*64 + j];
    acc += h[3] * pw1[3*64 + j];
    G[(size_t)r * 64 + j] = gelu_exact(acc);
}

// ---------------- Projector stage 2: X = G @ pw2 + pb2  [NR,128] ------------
// W (32KB) in LDS staged once; G rows via wave-uniform s_load_dwordx4.
__global__ void __launch_bounds__(512) proj2_kernel(const float* __restrict__ G,
        const float* __restrict__ pw2, const float* __restrict__ pb2,
        float* __restrict__ X) {
    __shared__ float Wc[64*128];     // 32KB
    int wave = threadIdx.x >> 6, lane = threadIdx.x & 63;
    for (int i = threadIdx.x; i < 64*128/4; i += 512)
        ((float4*)Wc)[i] = ((const float4*)pw2)[i];
    __syncthreads();
    float2 bv = ((const float2*)pb2)[lane];
    for (int tile = blockIdx.x * 8 + wave; tile < NR/8; tile += 192*8) {
        int rb = __builtin_amdgcn_readfirstlane(tile) * 8;
        const float* __restrict__ x0 = G + (size_t)rb * 64;
        float2 acc[8];
        #pragma unroll
        for (int r = 0; r < 8; ++r) acc[r] = make_float2(0.f, 0.f);
        #pragma unroll 2
        for (int k4 = 0; k4 < 16; ++k4) {
            float4 xr[8];
            #pragma unroll
            for (int r = 0; r < 8; ++r)
                xr[r] = *(const float4*)(x0 + r*64 + k4*4);   // s_load_dwordx4
            #pragma unroll
            for (int kk = 0; kk < 4; ++kk) {
                float2 w = ((const float2*)(Wc + (k4*4 + kk)*128))[lane];
                #pragma unroll
                for (int r = 0; r < 8; ++r) {
                    float xv = ((const float*)&xr[r])[kk];    // SGPR operand
                    acc[r].x += xv * w.x;
                    acc[r].y += xv * w.y;
                }
            }
        }
        #pragma unroll
        for (int r = 0; r < 8; ++r) {
            float2 o; o.x = acc[r].x + bv.x; o.y = acc[r].y + bv.y;
            ((float2*)(X + (size_t)(rb + r) * 128))[lane] = o;
        }
    }
}

// ---------------- fc1 + LayerNorm: H = LN(X @ W1 + b1)  [NR,256] ------------
// W in 64KB K-halves; x rows via s_load_dwordx4 (scalar pipe).
// Grid: 192 blocks x 8 waves = 1536 slots == NR/8 tiles (uniform barriers).
__global__ void __launch_bounds__(512) fc1_kernel(const float* __restrict__ Xin,
        const float* __restrict__ W, const float* __restrict__ bias,
        const float* __restrict__ gamma, const float* __restrict__ beta,
        float* __restrict__ Hout) {
    __shared__ float Wc[64*256];     // 64KB: K-half (64 x 256)
    int wave = threadIdx.x >> 6, lane = threadIdx.x & 63;
    float4 bv  = ((const float4*)bias)[lane];
    float4 gv  = ((const float4*)gamma)[lane];
    float4 btv = ((const float4*)beta)[lane];
    for (int tile = blockIdx.x * 8 + wave; tile < NR/8; tile += 192*8) {
        int rb = __builtin_amdgcn_readfirstlane(tile) * 8;
        const float* __restrict__ x0 = Xin + (size_t)rb * 128;
        float4 acc[8];
        #pragma unroll
        for (int r = 0; r < 8; ++r) acc[r] = make_float4(0.f,0.f,0.f,0.f);
        for (int h = 0; h < 2; ++h) {
            __syncthreads();
            const float4* Wh = (const float4*)(W + h*64*256);
            for (int i = threadIdx.x; i < 64*256/4; i += 512)
                ((float4*)Wc)[i] = Wh[i];
            __syncthreads();
            const float* __restrict__ xh = x0 + h*64;
            #pragma unroll 2
            for (int k4 = 0; k4 < 16; ++k4) {
                float4 xr[8];
                #pragma unroll
                for (int r = 0; r < 8; ++r)
                    xr[r] = *(const float4*)(xh + r*128 + k4*4);   // s_load_dwordx4
                #pragma unroll
                for (int kk = 0; kk < 4; ++kk) {
                    float4 w = ((const float4*)(Wc + (k4*4 + kk)*256))[lane];
                    #pragma unroll
                    for (int r = 0; r < 8; ++r) {
                        float xv = ((const float*)&xr[r])[kk];     // SGPR operand
                        acc[r].x += xv * w.x; acc[r].y += xv * w.y;
                        acc[r].z += xv * w.z; acc[r].w += xv * w.w;
                    }
                }
            }
        }
        #pragma unroll
        for (int r = 0; r < 8; ++r) {
            float4 a = acc[r];
            a.x += bv.x; a.y += bv.y; a.z += bv.z; a.w += bv.w;
            float s = a.x + a.y + a.z + a.w;
            #pragma unroll
            for (int m = 1; m < 64; m <<= 1) s += __shfl_xor(s, m, 64);
            float mean = s * (1.0f/256.0f);
            float dx = a.x - mean, dy = a.y - mean, dz = a.z - mean, dw = a.w - mean;
            float q2 = dx*dx + dy*dy + dz*dz + dw*dw;
            #pragma unroll
            for (int m = 1; m < 64; m <<= 1) q2 += __shfl_xor(q2, m, 64);
            float inv = 1.0f / sqrtf(q2 * (1.0f/256.0f) + 1e-5f);
            float4 o;
            o.x = dx*inv*gv.x + btv.x; o.y = dy*inv*gv.y + btv.y;
            o.z = dz*inv*gv.z + btv.z; o.w = dw*inv*gv.w + btv.w;
            ((float4*)(Hout + (size_t)(rb + r) * 256))[lane] = o;
        }
    }
}

// ---------------- LIF1: in-place H -> spike floats, full window per thread --
__global__ void lif1_kernel(float* __restrict__ H) {
    int tid = blockIdx.x * 256 + threadIdx.x;     // 64*256 = 16384 threads
    int d = tid & 255, b = tid >> 8;
    float* __restrict__ p = H + (size_t)b * TW * 256 + d;
    float v = 0.f;
    #pragma unroll 8
    for (int i = 0; i < TW; ++i) {
        float x = *p;
        v += (x - v) * 0.5f;
        bool s = (v >= 1.f);
        *p = s ? 1.f : 0.f;
        p += 256;
        v = s ? 0.f : v;
    }
}

// ---------------- fc2 + LayerNorm: Y = LN(H_spk @ W2 + b2)  [NR,128] --------
__global__ void __launch_bounds__(512) fc2_kernel(const float* __restrict__ SF,
        const float* __restrict__ W, const float* __restrict__ bias,
        const float* __restrict__ gamma, const float* __restrict__ beta,
        float* __restrict__ Y) {
    __shared__ float Wc[128*128];    // 64KB: K-half (128 x 128)
    int wave = threadIdx.x >> 6, lane = threadIdx.x & 63;
    float2 bv  = ((const float2*)bias)[lane];
    float2 gv  = ((const float2*)gamma)[lane];
    float2 btv = ((const float2*)beta)[lane];
    for (int tile = blockIdx.x * 8 + wave; tile < NR/8; tile += 192*8) {
        int rb = __builtin_amdgcn_readfirstlane(tile) * 8;
        const float* __restrict__ x0 = SF + (size_t)rb * 256;
        float2 acc[8];
        #pragma unroll
        for (int r = 0; r < 8; ++r) acc[r] = make_float2(0.f, 0.f);
        for (int h = 0; h < 2; ++h) {
            __syncthreads();
            const float4* Wh = (const float4*)(W + h*128*128);
            for (int i = threadIdx.x; i < 128*128/4; i += 512)
                ((float4*)Wc)[i] = Wh[i];
            __syncthreads();
            const float* __restrict__ xh = x0 + h*128;
            #pragma unroll 2
            for (int k4 = 0; k4 < 32; ++k4) {
                float4 xr[8];
                #pragma unroll
                for (int r = 0; r < 8; ++r)
                    xr[r] = *(const float4*)(xh + r*256 + k4*4);   // s_load_dwordx4
                #pragma unroll
                for (int kk = 0; kk < 4; ++kk) {
                    float2 w = ((const float2*)(Wc + (k4*4 + kk)*128))[lane];
                    #pragma unroll
                    for (int r = 0; r < 8; ++r) {
                        float xv = ((const float*)&xr[r])[kk];
                        acc[r].x += xv * w.x;
                        acc[r].y += xv * w.y;
                    }
                }
            }
        }
        #pragma unroll
        for (int r = 0; r < 8; ++r) {
            float2 a = acc[r];
            a.x += bv.x; a.y += bv.y;
            float s = a.x + a.y;
            #pragma unroll
            for (int m = 1; m < 64; m <<= 1) s += __shfl_xor(s, m, 64);
            float mean = s * (1.0f/128.0f);
            float dx = a.x - mean, dy = a.y - mean;
            float q = dx*dx + dy*dy;
            #pragma unroll
            for (int m = 1; m < 64; m <<= 1) q += __shfl_xor(q, m, 64);
            float inv = 1.0f / sqrtf(q * (1.0f/128.0f) + 1e-5f);
            float2 o;
            o.x = dx*inv*gv.x + btv.x;
            o.y = dy*inv*gv.y + btv.y;
            ((float2*)(Y + (size_t)(rb + r) * 128))[lane] = o;
        }
    }
}

// ---------------- LIF2 + residual add into X; final-layer output -----------
__global__ void lif2_kernel(const float* __restrict__ Y, float* __restrict__ X,
                            float* __restrict__ out, int writeOut) {
    int tid = blockIdx.x * 256 + threadIdx.x;     // 64*128 = 8192 threads
    int n = tid & 127, b = tid >> 7;
    const float* __restrict__ yp = Y + (size_t)b * TW * 128 + n;
    float* __restrict__ xp = X + (size_t)b * TW * 128 + n;
    float v = 0.f, xlast = 0.f;
    #pragma unroll 8
    for (int i = 0; i < TW; ++i) {
        float y = *yp; yp += 128;
        v += (y - v) * 0.5f;
        bool s = (v >= 1.f);
        float x = *xp + (s ? 1.f : 0.f);          // unconditional, prefetchable
        *xp = x; xp += 128;
        xlast = x;
        v = s ? 0.f : v;
    }
    if (writeOut) out[b * 128 + n] = xlast;       // row t=2047 per (b,n)
}

extern "C" void kernel_launch(void* const* d_in, const int* in_sizes, int n_in,
                              void* d_out, int out_size, void* d_ws, size_t ws_size,
                              hipStream_t stream) {
    const float* hist = (const float*)d_in[0];
    const float* pw1  = (const float*)d_in[1];
    const float* pb1  = (const float*)d_in[2];
    const float* pw2  = (const float*)d_in[3];
    const float* pb2  = (const float*)d_in[4];
    const float* fc1w = (const float*)d_in[5];
    const float* fc1b = (const float*)d_in[6];
    const float* n1g  = (const float*)d_in[7];
    const float* n1b  = (const float*)d_in[8];
    const float* fc2w = (const float*)d_in[9];
    const float* fc2b = (const float*)d_in[10];
    const float* n2g  = (const float*)d_in[11];
    const float* n2b  = (const float*)d_in[12];
    float* out = (float*)d_out;

    char* ws = (char*)d_ws;
    float* X = (float*)ws;                      // [NR,128] f32: 6 MiB
    float* H = (float*)(ws + (8ull<<20));       // [NR,256] f32: 12 MiB (also G, spikes)
    float* Y = (float*)(ws + (24ull<<20));      // [NR,128] f32: 6 MiB
    float* G = H;

    proj1_kernel<<<NR*64/256, 256, 0, stream>>>(hist, pw1, pb1, G);
    proj2_kernel<<<192, 512, 0, stream>>>(G, pw2, pb2, X);
    for (int l = 0; l < 4; ++l) {
        fc1_kernel<<<192, 512, 0, stream>>>(X, fc1w + (size_t)l*128*256,
                                            fc1b + l*256, n1g + l*256, n1b + l*256, H);
        lif1_kernel<<<64, 256, 0, stream>>>(H);
        fc2_kernel<<<192, 512, 0, stream>>>(H, fc2w + (size_t)l*256*128,
                                            fc2b + l*128, n2g + l*128, n2b + l*128, Y);
        lif2_kernel<<<32, 256, 0, stream>>>(Y, X, out, (l == 3) ? 1 : 0);
    }
}

// Round 7
// 257.903 us; speedup vs baseline: 9.4427x; 1.5395x over previous
//
#include <hip/hip_runtime.h>
#include <math.h>

// Problem constants
#define NB   64
#define TT   2048
// Tail-window truncation: output = x[:, 2047]; the only temporal coupling is
// the LIF membrane (decay 0.5/step + hard reset; LN/fc/residual are per-t).
// Computing t in [T0, 2048) with v(T0)=0: direct error at 2047 is 0.5^63,
// cascade-flip expectation ~1e-12 across all chains/stages. Same 64-step
// decay argument as the R4-validated warmup; R6 (TW=192) matched full-scan
// absmax exactly.
#define TW   64
#define T0   (TT - TW)     // 1984
#define NR   (NB * TW)     // 4096 active rows

__device__ __forceinline__ float gelu_exact(float x) {
    return 0.5f * x * (1.0f + erff(x * 0.7071067811865476f));
}

// ---------------- Projector stage 1: G = gelu(hist @ pw1 + pb1)  [NR,64] ----
__global__ void proj1_kernel(const float* __restrict__ hist, const float* __restrict__ pw1,
                             const float* __restrict__ pb1, float* __restrict__ G) {
    int tid = blockIdx.x * 256 + threadIdx.x;     // NR*64 threads
    int r = tid >> 6, j = tid & 63;
    int b = r >> 6, t = r & (TW - 1);              // window-local row -> (b, T0+t)
    const float* h = hist + ((size_t)b * TT + (T0 + t)) * 4;
    float acc = pb1[j];
    acc += h[0] * pw1[0*64 + j];
    acc += h[1] * pw1[1*64 + j];
    acc += h[2] * pw1[2*64 + j];
    acc += h[3] * pw1[3*64 + j];
    G[(size_t)r * 64 + j] = gelu_exact(acc);
}

// ---------------- Projector stage 2: X = G @ pw2 + pb2  [NR,128] ------------
// W (32KB) in LDS staged once; G rows via wave-uniform s_load_dwordx4.
// Grid: 64 blocks x 8 waves = 512 slots == NR/8 tiles.
__global__ void __launch_bounds__(512) proj2_kernel(const float* __restrict__ G,
        const float* __restrict__ pw2, const float* __restrict__ pb2,
        float* __restrict__ X) {
    __shared__ float Wc[64*128];     // 32KB
    int wave = threadIdx.x >> 6, lane = threadIdx.x & 63;
    for (int i = threadIdx.x; i < 64*128/4; i += 512)
        ((float4*)Wc)[i] = ((const float4*)pw2)[i];
    __syncthreads();
    float2 bv = ((const float2*)pb2)[lane];
    int tile = blockIdx.x * 8 + wave;             // exact fit: 512 tiles
    int rb = __builtin_amdgcn_readfirstlane(tile) * 8;
    const float* __restrict__ x0 = G + (size_t)rb * 64;
    float2 acc[8];
    #pragma unroll
    for (int r = 0; r < 8; ++r) acc[r] = make_float2(0.f, 0.f);
    #pragma unroll 2
    for (int k4 = 0; k4 < 16; ++k4) {
        float4 xr[8];
        #pragma unroll
        for (int r = 0; r < 8; ++r)
            xr[r] = *(const float4*)(x0 + r*64 + k4*4);   // s_load_dwordx4
        #pragma unroll
        for (int kk = 0; kk < 4; ++kk) {
            float2 w = ((const float2*)(Wc + (k4*4 + kk)*128))[lane];
            #pragma unroll
            for (int r = 0; r < 8; ++r) {
                float xv = ((const float*)&xr[r])[kk];    // SGPR operand
                acc[r].x += xv * w.x;
                acc[r].y += xv * w.y;
            }
        }
    }
    #pragma unroll
    for (int r = 0; r < 8; ++r) {
        float2 o; o.x = acc[r].x + bv.x; o.y = acc[r].y + bv.y;
        ((float2*)(X + (size_t)(rb + r) * 128))[lane] = o;
    }
}

// ---------------- fc1 + LayerNorm: H = LN(X @ W1 + b1)  [NR,256] ------------
// 4-row tiles to spread across 128 blocks (grid-spread > per-CU occupancy at
// this size). W in 64KB K-halves; x rows via s_load_dwordx4 (scalar pipe).
// Grid: 128 blocks x 8 waves = 1024 slots == NR/4 tiles.
__global__ void __launch_bounds__(512) fc1_kernel(const float* __restrict__ Xin,
        const float* __restrict__ W, const float* __restrict__ bias,
        const float* __restrict__ gamma, const float* __restrict__ beta,
        float* __restrict__ Hout) {
    __shared__ float Wc[64*256];     // 64KB: K-half (64 x 256)
    int wave = threadIdx.x >> 6, lane = threadIdx.x & 63;
    float4 bv  = ((const float4*)bias)[lane];
    float4 gv  = ((const float4*)gamma)[lane];
    float4 btv = ((const float4*)beta)[lane];
    int tile = blockIdx.x * 8 + wave;             // exact fit: 1024 tiles
    int rb = __builtin_amdgcn_readfirstlane(tile) * 4;
    const float* __restrict__ x0 = Xin + (size_t)rb * 128;
    float4 acc[4];
    #pragma unroll
    for (int r = 0; r < 4; ++r) acc[r] = make_float4(0.f,0.f,0.f,0.f);
    for (int h = 0; h < 2; ++h) {
        __syncthreads();
        const float4* Wh = (const float4*)(W + h*64*256);
        for (int i = threadIdx.x; i < 64*256/4; i += 512)
            ((float4*)Wc)[i] = Wh[i];
        __syncthreads();
        const float* __restrict__ xh = x0 + h*64;
        #pragma unroll 2
        for (int k4 = 0; k4 < 16; ++k4) {
            float4 xr[4];
            #pragma unroll
            for (int r = 0; r < 4; ++r)
                xr[r] = *(const float4*)(xh + r*128 + k4*4);   // s_load_dwordx4
            #pragma unroll
            for (int kk = 0; kk < 4; ++kk) {
                float4 w = ((const float4*)(Wc + (k4*4 + kk)*256))[lane];
                #pragma unroll
                for (int r = 0; r < 4; ++r) {
                    float xv = ((const float*)&xr[r])[kk];     // SGPR operand
                    acc[r].x += xv * w.x; acc[r].y += xv * w.y;
                    acc[r].z += xv * w.z; acc[r].w += xv * w.w;
                }
            }
        }
    }
    #pragma unroll
    for (int r = 0; r < 4; ++r) {
        float4 a = acc[r];
        a.x += bv.x; a.y += bv.y; a.z += bv.z; a.w += bv.w;
        float s = a.x + a.y + a.z + a.w;
        #pragma unroll
        for (int m = 1; m < 64; m <<= 1) s += __shfl_xor(s, m, 64);
        float mean = s * (1.0f/256.0f);
        float dx = a.x - mean, dy = a.y - mean, dz = a.z - mean, dw = a.w - mean;
        float q2 = dx*dx + dy*dy + dz*dz + dw*dw;
        #pragma unroll
        for (int m = 1; m < 64; m <<= 1) q2 += __shfl_xor(q2, m, 64);
        float inv = 1.0f / sqrtf(q2 * (1.0f/256.0f) + 1e-5f);
        float4 o;
        o.x = dx*inv*gv.x + btv.x; o.y = dy*inv*gv.y + btv.y;
        o.z = dz*inv*gv.z + btv.z; o.w = dw*inv*gv.w + btv.w;
        ((float4*)(Hout + (size_t)(rb + r) * 256))[lane] = o;
    }
}

// ---------------- LIF1: in-place H -> spike floats, full window per thread --
__global__ void lif1_kernel(float* __restrict__ H) {
    int tid = blockIdx.x * 256 + threadIdx.x;     // 64*256 = 16384 threads
    int d = tid & 255, b = tid >> 8;
    float* __restrict__ p = H + (size_t)b * TW * 256 + d;
    float v = 0.f;
    #pragma unroll 8
    for (int i = 0; i < TW; ++i) {
        float x = *p;
        v += (x - v) * 0.5f;
        bool s = (v >= 1.f);
        *p = s ? 1.f : 0.f;
        p += 256;
        v = s ? 0.f : v;
    }
}

// ---------------- fc2 + LayerNorm: Y = LN(H_spk @ W2 + b2)  [NR,128] --------
// 8-row tiles (float2 acc would go LDS-bound at 4 rows). Grid: 64 x 8 = 512.
__global__ void __launch_bounds__(512) fc2_kernel(const float* __restrict__ SF,
        const float* __restrict__ W, const float* __restrict__ bias,
        const float* __restrict__ gamma, const float* __restrict__ beta,
        float* __restrict__ Y) {
    __shared__ float Wc[128*128];    // 64KB: K-half (128 x 128)
    int wave = threadIdx.x >> 6, lane = threadIdx.x & 63;
    float2 bv  = ((const float2*)bias)[lane];
    float2 gv  = ((const float2*)gamma)[lane];
    float2 btv = ((const float2*)beta)[lane];
    int tile = blockIdx.x * 8 + wave;             // exact fit: 512 tiles
    int rb = __builtin_amdgcn_readfirstlane(tile) * 8;
    const float* __restrict__ x0 = SF + (size_t)rb * 256;
    float2 acc[8];
    #pragma unroll
    for (int r = 0; r < 8; ++r) acc[r] = make_float2(0.f, 0.f);
    for (int h = 0; h < 2; ++h) {
        __syncthreads();
        const float4* Wh = (const float4*)(W + h*128*128);
        for (int i = threadIdx.x; i < 128*128/4; i += 512)
            ((float4*)Wc)[i] = Wh[i];
        __syncthreads();
        const float* __restrict__ xh = x0 + h*128;
        #pragma unroll 2
        for (int k4 = 0; k4 < 32; ++k4) {
            float4 xr[8];
            #pragma unroll
            for (int r = 0; r < 8; ++r)
                xr[r] = *(const float4*)(xh + r*256 + k4*4);   // s_load_dwordx4
            #pragma unroll
            for (int kk = 0; kk < 4; ++kk) {
                float2 w = ((const float2*)(Wc + (k4*4 + kk)*128))[lane];
                #pragma unroll
                for (int r = 0; r < 8; ++r) {
                    float xv = ((const float*)&xr[r])[kk];
                    acc[r].x += xv * w.x;
                    acc[r].y += xv * w.y;
                }
            }
        }
    }
    #pragma unroll
    for (int r = 0; r < 8; ++r) {
        float2 a = acc[r];
        a.x += bv.x; a.y += bv.y;
        float s = a.x + a.y;
        #pragma unroll
        for (int m = 1; m < 64; m <<= 1) s += __shfl_xor(s, m, 64);
        float mean = s * (1.0f/128.0f);
        float dx = a.x - mean, dy = a.y - mean;
        float q = dx*dx + dy*dy;
        #pragma unroll
        for (int m = 1; m < 64; m <<= 1) q += __shfl_xor(q, m, 64);
        float inv = 1.0f / sqrtf(q * (1.0f/128.0f) + 1e-5f);
        float2 o;
        o.x = dx*inv*gv.x + btv.x;
        o.y = dy*inv*gv.y + btv.y;
        ((float2*)(Y + (size_t)(rb + r) * 128))[lane] = o;
    }
}

// ---------------- LIF2 + residual add into X; final-layer output -----------
__global__ void lif2_kernel(const float* __restrict__ Y, float* __restrict__ X,
                            float* __restrict__ out, int writeOut) {
    int tid = blockIdx.x * 256 + threadIdx.x;     // 64*128 = 8192 threads
    int n = tid & 127, b = tid >> 7;
    const float* __restrict__ yp = Y + (size_t)b * TW * 128 + n;
    float* __restrict__ xp = X + (size_t)b * TW * 128 + n;
    float v = 0.f, xlast = 0.f;
    #pragma unroll 8
    for (int i = 0; i < TW; ++i) {
        float y = *yp; yp += 128;
        v += (y - v) * 0.5f;
        bool s = (v >= 1.f);
        float x = *xp + (s ? 1.f : 0.f);          // unconditional, prefetchable
        *xp = x; xp += 128;
        xlast = x;
        v = s ? 0.f : v;
    }
    if (writeOut) out[b * 128 + n] = xlast;       // row t=2047 per (b,n)
}

extern "C" void kernel_launch(void* const* d_in, const int* in_sizes, int n_in,
                              void* d_out, int out_size, void* d_ws, size_t ws_size,
                              hipStream_t stream) {
    const float* hist = (const float*)d_in[0];
    const float* pw1  = (const float*)d_in[1];
    const float* pb1  = (const float*)d_in[2];
    const float* pw2  = (const float*)d_in[3];
    const float* pb2  = (const float*)d_in[4];
    const float* fc1w = (const float*)d_in[5];
    const float* fc1b = (const float*)d_in[6];
    const float* n1g  = (const float*)d_in[7];
    const float* n1b  = (const float*)d_in[8];
    const float* fc2w = (const float*)d_in[9];
    const float* fc2b = (const float*)d_in[10];
    const float* n2g  = (const float*)d_in[11];
    const float* n2b  = (const float*)d_in[12];
    float* out = (float*)d_out;

    char* ws = (char*)d_ws;
    float* X = (float*)ws;                      // [NR,128] f32: 2 MiB
    float* H = (float*)(ws + (4ull<<20));       // [NR,256] f32: 4 MiB (also G, spikes)
    float* Y = (float*)(ws + (12ull<<20));      // [NR,128] f32: 2 MiB
    float* G = H;

    proj1_kernel<<<NR*64/256, 256, 0, stream>>>(hist, pw1, pb1, G);
    proj2_kernel<<<64, 512, 0, stream>>>(G, pw2, pb2, X);
    for (int l = 0; l < 4; ++l) {
        fc1_kernel<<<128, 512, 0, stream>>>(X, fc1w + (size_t)l*128*256,
                                            fc1b + l*256, n1g + l*256, n1b + l*256, H);
        lif1_kernel<<<64, 256, 0, stream>>>(H);
        fc2_kernel<<<64, 512, 0, stream>>>(H, fc2w + (size_t)l*256*128,
                                           fc2b + l*128, n2g + l*128, n2b + l*128, Y);
        lif2_kernel<<<32, 256, 0, stream>>>(Y, X, out, (l == 3) ? 1 : 0);
    }
}